// Round 9
// baseline (917.807 us; speedup 1.0000x reference)
//
#include <hip/hip_runtime.h>
#include <hip/hip_bf16.h>

#define DEPTH   6
#define DIM     192
#define HEADS   12
#define DH      16
#define MLPD    768
#define SEQ     256
#define BATCH   32
#define ROWS    (BATCH*SEQ)   // 8192

typedef __attribute__((ext_vector_type(8))) short short8;
typedef __attribute__((ext_vector_type(4))) float f32x4;
typedef __attribute__((ext_vector_type(4))) _Float16 half4;
typedef __hip_bfloat16 bf16_t;
typedef _Float16 f16_t;

__device__ __forceinline__ bf16_t f2b(float v){ return __float2bfloat16(v); }
__device__ __forceinline__ ushort f2u(float v){
    union{ bf16_t b; ushort u; } w; w.b = __float2bfloat16(v); return w.u;
}
__device__ __forceinline__ f16_t u2h(ushort u){ union{ ushort u; f16_t h; } w; w.u = u; return w.h; }
__device__ __forceinline__ ushort h2u(f16_t h){ union{ ushort u; f16_t h; } w; w.h = h; return w.u; }

// async global->LDS, 16B per lane. LDS dest = wave-uniform base + lane*16B.
__device__ __forceinline__ void async16(ushort* lds, const ushort* gp){
    __builtin_amdgcn_global_load_lds(
        (const __attribute__((address_space(1))) uint*)gp,
        (__attribute__((address_space(3))) uint*)lds, 16, 0, 0);
}

// ---------------- residual init ----------------
__global__ void copy_kernel(const float* __restrict__ x, float* __restrict__ xr, int n){
    int i = blockIdx.x*256 + threadIdx.x;
    if (i < n) xr[i] = x[i];
}

// ---------------- weight transpose-convert: W[l][K][N] fp32 -> WT[l][N][K] bf16 ----
__global__ __launch_bounds__(256) void wt_kernel(const float* __restrict__ W,
        ushort* __restrict__ WT, int K, int N){
    __shared__ ushort T[64*72];
    int l = blockIdx.z;
    const float* src = W + ((size_t)l*K + blockIdx.x*64)*N + blockIdx.y*64;
    ushort* dst = WT + ((size_t)l*N + blockIdx.y*64)*K + blockIdx.x*64;
    int tid = threadIdx.x;
    int r = tid >> 2, c4 = (tid & 3)*16;
    #pragma unroll
    for (int u=0; u<4; u++){
        float4 v = *(const float4*)(src + (size_t)r*N + c4 + u*4);
        T[(c4+u*4+0)*72 + r] = f2u(v.x);
        T[(c4+u*4+1)*72 + r] = f2u(v.y);
        T[(c4+u*4+2)*72 + r] = f2u(v.z);
        T[(c4+u*4+3)*72 + r] = f2u(v.w);
    }
    __syncthreads();
    int n = tid >> 2, k8 = (tid & 3)*16;
    #pragma unroll
    for (int u=0; u<2; u++)
        *(uint4*)(dst + (size_t)n*K + k8 + u*8) = *(uint4*)&T[n*72 + k8 + u*8];
}

// ------- fused LN + GEMM, K=192, B-frags DIRECT from global (no Bs, 1 barrier) -------
// MODE 0: QKV -> out0 (f16 stride 192) for cols<192, else out1 (f16 stride 384)
// MODE 1: W1  -> +bias, exact GELU, bf16 to out0 (stride MLPD)
template<int MODE, int NT>
__global__ __launch_bounds__(256) void gemm_ln_kernel(
        const float* __restrict__ xres, const float* __restrict__ ln_g,
        const float* __restrict__ ln_b, const ushort* __restrict__ BT0,
        const ushort* __restrict__ BT1, const float* __restrict__ bias,
        f16_t* __restrict__ out0, f16_t* __restrict__ out1){
    __shared__ ushort As[64*200];      // LN'd A rows, stride 200 (2-way banks)
    int tid = threadIdx.x, lane = tid & 63, w = tid >> 6;
    int bm = blockIdx.x*64;
    int tile0 = blockIdx.y*NT;
    // LN prologue: each block LNs its 64 rows ONCE
    float g0 = ln_g[lane], g1 = ln_g[lane+64], g2 = ln_g[lane+128];
    float e0 = ln_b[lane], e1 = ln_b[lane+64], e2 = ln_b[lane+128];
    for (int it = 0; it < 16; it++){
        int r = (w<<4) + it;
        const float* xr = xres + (size_t)(bm + r)*DIM;
        float v0 = xr[lane], v1 = xr[lane+64], v2 = xr[lane+128];
        float s = v0+v1+v2;
        #pragma unroll
        for (int off=32; off; off>>=1) s += __shfl_xor(s, off, 64);
        float m = s*(1.0f/192.0f);
        float d0=v0-m, d1=v1-m, d2=v2-m;
        float q = d0*d0+d1*d1+d2*d2;
        #pragma unroll
        for (int off=32; off; off>>=1) q += __shfl_xor(q, off, 64);
        float inv = rsqrtf(q*(1.0f/192.0f) + 1e-5f);
        ushort* dst = &As[r*200];
        dst[lane]     = f2u(d0*inv*g0 + e0);
        dst[lane+64]  = f2u(d1*inv*g1 + e1);
        dst[lane+128] = f2u(d2*inv*g2 + e2);
    }
    __syncthreads();   // the ONLY barrier
    int wrow = w >> 1, wcol = w & 1;
    int quad = lane >> 4, mr = lane & 15;
    for (int t = 0; t < NT; t++){
        int bn = (tile0 + t)*64;
        const ushort* bt; int bnl;
        if (MODE == 0 && bn >= DIM){ bt = BT1; bnl = bn - DIM; }
        else { bt = BT0; bnl = bn; }
        const ushort* b0p = bt + (size_t)(bnl + wcol*32 + mr)*DIM;
        const ushort* b1p = b0p + (size_t)16*DIM;
        f32x4 acc[2][2] = {};
        #pragma unroll
        for (int c = 0; c < 6; c++){
            short8 a0 = *(const short8*)&As[(wrow*32+mr)*200    + c*32 + quad*8];
            short8 a1 = *(const short8*)&As[(wrow*32+16+mr)*200 + c*32 + quad*8];
            short8 b0 = *(const short8*)(b0p + c*32 + quad*8);
            short8 b1 = *(const short8*)(b1p + c*32 + quad*8);
            acc[0][0] = __builtin_amdgcn_mfma_f32_16x16x32_bf16(a0, b0, acc[0][0], 0,0,0);
            acc[0][1] = __builtin_amdgcn_mfma_f32_16x16x32_bf16(a0, b1, acc[0][1], 0,0,0);
            acc[1][0] = __builtin_amdgcn_mfma_f32_16x16x32_bf16(a1, b0, acc[1][0], 0,0,0);
            acc[1][1] = __builtin_amdgcn_mfma_f32_16x16x32_bf16(a1, b1, acc[1][1], 0,0,0);
        }
        #pragma unroll
        for (int rr=0; rr<2; rr++){
            #pragma unroll
            for (int cc=0; cc<2; cc++){
                int col = bn + wcol*32 + cc*16 + mr;
                if (MODE == 0){
                    f16_t* op; size_t st;
                    if (col < DIM){ op = out0 + col; st = DIM; }
                    else          { op = out1 + (col - DIM); st = 2*DIM; }
                    #pragma unroll
                    for (int tt=0; tt<4; tt++){
                        int row = bm + wrow*32 + rr*16 + quad*4 + tt;
                        op[(size_t)row*st] = (f16_t)acc[rr][cc][tt];
                    }
                } else {
                    float bv = bias[col];
                    #pragma unroll
                    for (int tt=0; tt<4; tt++){
                        int row = bm + wrow*32 + rr*16 + quad*4 + tt;
                        float z = acc[rr][cc][tt] + bv;
                        ((bf16_t*)out0)[(size_t)row*MLPD + col] =
                            f2b(0.5f*z*(1.0f + erff(z*0.70710678118654752f)));
                    }
                }
            }
        }
    }
}

// ------- GEMM + residual: xres += (A@B^T + bias)*ls. ZERO LDS, zero barriers -------
// A and B fragments are direct 16B global loads (both operands L2-resident).
template<int ROUNDS>
__global__ __launch_bounds__(256) void gemm_a_kernel(
        const ushort* __restrict__ A, const ushort* __restrict__ BT,
        const float* __restrict__ bias, const float* __restrict__ ls,
        float* __restrict__ xres){
    const int K = ROUNDS*192;
    int tid = threadIdx.x, lane = tid & 63, w = tid >> 6;
    int wrow = w >> 1, wcol = w & 1;
    int bm = blockIdx.x*64, bn = blockIdx.y*64;
    int quad = lane >> 4, mr = lane & 15;
    const ushort* a0p = A  + (size_t)(bm + wrow*32 + mr)*K;
    const ushort* a1p = a0p + (size_t)16*K;
    const ushort* b0p = BT + (size_t)(bn + wcol*32 + mr)*K;
    const ushort* b1p = b0p + (size_t)16*K;
    f32x4 acc[2][2] = {};
    #pragma unroll 6
    for (int c = 0; c < ROUNDS*6; c++){
        int k0 = c*32 + quad*8;
        short8 a0 = *(const short8*)(a0p + k0);
        short8 a1 = *(const short8*)(a1p + k0);
        short8 b0 = *(const short8*)(b0p + k0);
        short8 b1 = *(const short8*)(b1p + k0);
        acc[0][0] = __builtin_amdgcn_mfma_f32_16x16x32_bf16(a0, b0, acc[0][0], 0,0,0);
        acc[0][1] = __builtin_amdgcn_mfma_f32_16x16x32_bf16(a0, b1, acc[0][1], 0,0,0);
        acc[1][0] = __builtin_amdgcn_mfma_f32_16x16x32_bf16(a1, b0, acc[1][0], 0,0,0);
        acc[1][1] = __builtin_amdgcn_mfma_f32_16x16x32_bf16(a1, b1, acc[1][1], 0,0,0);
    }
    #pragma unroll
    for (int rr=0; rr<2; rr++){
        #pragma unroll
        for (int cc=0; cc<2; cc++){
            int col = bn + wcol*32 + cc*16 + mr;
            float bv = bias[col], lv = ls[col];
            #pragma unroll
            for (int tt=0; tt<4; tt++){
                int row = bm + wrow*32 + rr*16 + quad*4 + tt;
                xres[(size_t)row*DIM + col] += (acc[rr][cc][tt] + bv)*lv;
            }
        }
    }
}

// ---------------- fused attention + Wo + residual (unchanged from R8) ----------------
#define SLAB    4488
#define IST     280
#define KV_OFF  53856
#define ROWP    200
#define Q_OFF   66656
#define PRE_OFF 69856
#define POST_OFF 70112
#define LTOT    71776

__global__ __launch_bounds__(512, 1) void attn_kernel(
        const f16_t* __restrict__ qb, const f16_t* __restrict__ kvb,
        const float* __restrict__ lsa, const float* __restrict__ pre,
        const float* __restrict__ post, const ushort* __restrict__ WoT,
        const float* __restrict__ bo, const float* __restrict__ ls1,
        float* __restrict__ xres){
    __shared__ ushort L[LTOT];
    int tid  = threadIdx.x;
    int lane = tid & 63, w = tid >> 6;
    int quad = lane >> 4, nr = lane & 15;
    int b  = blockIdx.x >> 4;
    int i0 = (blockIdx.x & 15) << 4;

    {
        uint* Z = (uint*)&L[KV_OFF];
        for (int k = tid; k < (LTOT - KV_OFF)/2; k += 512) Z[k] = 0;
    }
    __syncthreads();

    if (tid < 384){
        int e = tid*8, i = e/DIM, d = e%DIM, hh = d >> 4;
        float sc = lsa[hh];
        union { uint4 v; f16_t h[8]; } iv, ov;
        iv.v = *(const uint4*)(qb + (size_t)(b*SEQ + i0 + i)*DIM + d);
        #pragma unroll
        for (int u=0; u<8; u++) ov.h[u] = (f16_t)((float)iv.h[u]*sc);
        *(uint4*)&L[Q_OFF + i*ROWP + d] = ov.v;
    } else {
        for (int k = tid-384; k < 256; k += 128){
            int gg = k >> 4, hh = k & 15;
            if (gg < 12 && hh < 12)
                L[POST_OFF + k] = h2u((f16_t)post[hh*12+gg]);
        }
    }
    auto stage_kv = [&](int c, int coloff){
        #pragma unroll
        for (int s = 0; s < 3; s++){
            int e = (tid + s*512)*8;
            int j = e/DIM, d = e%DIM;
            uint4 v = *(const uint4*)(kvb + (size_t)(b*SEQ + c*64 + j)*(2*DIM) + coloff + d);
            *(uint4*)&L[KV_OFF + j*ROWP + d] = v;
        }
    };
    __syncthreads();

    half4 qf[12];
    #pragma unroll
    for (int h=0; h<12; h++)
        qf[h] = *(const half4*)&L[Q_OFF + nr*ROWP + h*16 + quad*4];
    half4 postTf = *(const half4*)&L[POST_OFF + nr*16 + quad*4];

    #pragma unroll
    for (int sub = 0; sub < 2; sub++){
        int jg = w*32 + sub*16 + nr;
        const f16_t* krow = kvb + (size_t)(b*SEQ + jg)*(2*DIM);
        f32x4 acc[12];
        #pragma unroll
        for (int h=0; h<12; h++){
            half4 bv = *(const half4*)(krow + h*DH + quad*4);
            acc[h] = __builtin_amdgcn_mfma_f32_16x16x16f16(qf[h], bv, (f32x4){0,0,0,0}, 0,0,0);
        }
        #pragma unroll
        for (int t=0; t<4; t++){
            if (i0 + quad*4 + t == jg){
                #pragma unroll
                for (int h=0; h<12; h++) acc[h][t] = -1e-9f;
            }
        }
        #pragma unroll
        for (int g=0; g<12; g++){
            float s0=0.f, s1=0.f, s2=0.f, s3=0.f;
            #pragma unroll
            for (int h=0; h<12; h++){
                float p = pre[h*12+g];
                s0 += acc[h][0]*p; s1 += acc[h][1]*p;
                s2 += acc[h][2]*p; s3 += acc[h][3]*p;
            }
            ushort* sp = &L[g*SLAB + jg];
            sp[(quad*4+0)*IST] = h2u((f16_t)s0);
            sp[(quad*4+1)*IST] = h2u((f16_t)s1);
            sp[(quad*4+2)*IST] = h2u((f16_t)s2);
            sp[(quad*4+3)*IST] = h2u((f16_t)s3);
        }
    }
    __syncthreads();

    for (int r = w; r < 192; r += 8){
        int g = r >> 4, i = r & 15;
        ushort* sp = &L[g*SLAB + i*IST];
        ushort4 uv = *(ushort4*)&sp[lane*4];
        float e0 = __expf((float)u2h(uv.x));
        float e1 = __expf((float)u2h(uv.y));
        float e2 = __expf((float)u2h(uv.z));
        float e3 = __expf((float)u2h(uv.w));
        float ssum = e0+e1+e2+e3;
        #pragma unroll
        for (int off=32; off; off>>=1) ssum += __shfl_xor(ssum, off, 64);
        float rin = 1.0f/ssum;
        uv.x = h2u((f16_t)(e0*rin)); uv.y = h2u((f16_t)(e1*rin));
        uv.z = h2u((f16_t)(e2*rin)); uv.w = h2u((f16_t)(e3*rin));
        *(ushort4*)&sp[lane*4] = uv;
    }
    __syncthreads();

    for (int s = 0; s < 32; s++){
        int cb = s*8 + w;
        int i = cb >> 4, jb = cb & 15;
        int colbase = i*IST + jb*16 + nr;
        half4 bv;
        #pragma unroll
        for (int t=0; t<4; t++) bv[t] = u2h(L[(quad*4+t)*SLAB + colbase]);
        f32x4 cc = __builtin_amdgcn_mfma_f32_16x16x16f16(postTf, bv, (f32x4){0,0,0,0}, 0,0,0);
        if (quad < 3){
            #pragma unroll
            for (int t=0; t<4; t++) L[(quad*4+t)*SLAB + colbase] = h2u((f16_t)cc[t]);
        }
    }
    __syncthreads();

    f32x4 oacc[2] = {{0,0,0,0},{0,0,0,0}};
    int g0 = w, g1 = (w < 4) ? 8 + w : -1;
    for (int c = 0; c < 4; c++){
        stage_kv(c, DIM);
        __syncthreads();
        #pragma unroll
        for (int sl = 0; sl < 2; sl++){
            int g = sl ? g1 : g0;
            if (g < 0) continue;
            #pragma unroll
            for (int ks = 0; ks < 4; ks++){
                int jl = ks*16 + quad*4;
                half4 av = *(const half4*)&L[g*SLAB + nr*IST + c*64 + jl];
                half4 bv;
                #pragma unroll
                for (int t=0; t<4; t++) bv[t] = u2h(L[KV_OFF + (jl+t)*ROWP + g*16 + nr]);
                oacc[sl] = __builtin_amdgcn_mfma_f32_16x16x16f16(av, bv, oacc[sl], 0,0,0);
            }
        }
        __syncthreads();
    }

    {
        #pragma unroll
        for (int s = 0; s < 9; s++){
            int e = (tid + s*512)*8;
            int c = e/12288, rem = e - c*12288;
            int n = rem >> 6, kk = rem & 63;
            async16(&L[e], WoT + (size_t)n*192 + c*64 + kk);
        }
        #pragma unroll
        for (int sl = 0; sl < 2; sl++){
            int g = sl ? g1 : g0;
            if (g < 0) continue;
            #pragma unroll
            for (int t=0; t<4; t++){
                int i = quad*4 + t;
                L[Q_OFF + i*ROWP + g*16 + nr] = f2u(oacc[sl][t]);
            }
        }
    }
    __syncthreads();

    {
        f32x4 wacc[2] = {{0,0,0,0},{0,0,0,0}};
        int ct0 = w, ct1 = (w < 4) ? 8 + w : -1;
        #pragma unroll
        for (int c = 0; c < 3; c++){
            #pragma unroll
            for (int sub = 0; sub < 2; sub++){
                int k0 = c*64 + sub*32;
                short8 av = *(const short8*)&L[Q_OFF + nr*ROWP + k0 + quad*8];
                #pragma unroll
                for (int sl = 0; sl < 2; sl++){
                    int ct = sl ? ct1 : ct0;
                    if (ct < 0) continue;
                    short8 bv = *(const short8*)&L[c*12288 + (ct*16 + nr)*64 + sub*32 + quad*8];
                    wacc[sl] = __builtin_amdgcn_mfma_f32_16x16x32_bf16(av, bv, wacc[sl], 0,0,0);
                }
            }
        }
        #pragma unroll
        for (int sl = 0; sl < 2; sl++){
            int ct = sl ? ct1 : ct0;
            if (ct < 0) continue;
            int col = ct*16 + nr;
            float bv = bo[col], lv = ls1[col];
            #pragma unroll
            for (int t=0; t<4; t++){
                int row = b*SEQ + i0 + quad*4 + t;
                xres[(size_t)row*DIM + col] += (wacc[sl][t] + bv)*lv;
            }
        }
    }
}

extern "C" void kernel_launch(void* const* d_in, const int* in_sizes, int n_in,
                              void* d_out, int out_size, void* d_ws, size_t ws_size,
                              hipStream_t stream){
    const float* x    = (const float*)d_in[0];
    const float* ln1g = (const float*)d_in[1];
    const float* ln1b = (const float*)d_in[2];
    const float* Wq   = (const float*)d_in[3];
    const float* Wkv  = (const float*)d_in[4];
    const float* lsa  = (const float*)d_in[5];
    const float* pre  = (const float*)d_in[6];
    const float* post = (const float*)d_in[7];
    const float* Wo   = (const float*)d_in[8];
    const float* bo   = (const float*)d_in[9];
    const float* ls1  = (const float*)d_in[10];
    const float* ln2g = (const float*)d_in[11];
    const float* ln2b = (const float*)d_in[12];
    const float* W1   = (const float*)d_in[13];
    const float* b1   = (const float*)d_in[14];
    const float* W2   = (const float*)d_in[15];
    const float* b2   = (const float*)d_in[16];
    const float* ls2  = (const float*)d_in[17];
    float* xres = (float*)d_out;             // fp32 residual lives in d_out

    char* ws = (char*)d_ws;
    f16_t*  qb  = (f16_t*)ws;
    f16_t*  kvb = (f16_t*)(ws + (size_t)ROWS*DIM*2);
    bf16_t* fb  = (bf16_t*)ws;               // overlaps qb/kvb (disjoint lifetimes)
    char* p = ws + (size_t)ROWS*MLPD*2;
    ushort* WqT  = (ushort*)p; p += (size_t)DEPTH*DIM*DIM*2;
    ushort* WkvT = (ushort*)p; p += (size_t)DEPTH*DIM*2*DIM*2;
    ushort* WoT  = (ushort*)p; p += (size_t)DEPTH*DIM*DIM*2;
    ushort* W1T  = (ushort*)p; p += (size_t)DEPTH*DIM*MLPD*2;
    ushort* W2T  = (ushort*)p; p += (size_t)DEPTH*MLPD*DIM*2;

    int ntot = ROWS*DIM;
    copy_kernel<<<ntot/256, 256, 0, stream>>>(x, xres, ntot);
    wt_kernel<<<dim3(3,3,6),  256, 0, stream>>>(Wq,  WqT,  DIM,  DIM);
    wt_kernel<<<dim3(3,6,6),  256, 0, stream>>>(Wkv, WkvT, DIM,  2*DIM);
    wt_kernel<<<dim3(3,3,6),  256, 0, stream>>>(Wo,  WoT,  DIM,  DIM);
    wt_kernel<<<dim3(3,12,6), 256, 0, stream>>>(W1,  W1T,  DIM,  MLPD);
    wt_kernel<<<dim3(12,3,6), 256, 0, stream>>>(W2,  W2T,  MLPD, DIM);
    for (int l = 0; l < DEPTH; l++){
        gemm_ln_kernel<0,3><<<dim3(128,3), 256, 0, stream>>>(xres,
                ln1g + l*DIM, ln1b + l*DIM,
                WqT + (size_t)l*DIM*DIM, WkvT + (size_t)l*DIM*2*DIM,
                nullptr, qb, kvb);
        attn_kernel<<<BATCH*(SEQ/16), 512, 0, stream>>>(qb, kvb, lsa + l*HEADS,
                pre + l*HEADS*HEADS, post + l*HEADS*HEADS,
                WoT + (size_t)l*DIM*DIM, bo + l*DIM, ls1 + l*DIM, xres);
        gemm_ln_kernel<1,4><<<dim3(128,3), 256, 0, stream>>>(xres,
                ln2g + l*DIM, ln2b + l*DIM,
                W1T + (size_t)l*DIM*MLPD, nullptr, b1 + l*MLPD, (f16_t*)fb, nullptr);
        gemm_a_kernel<4><<<dim3(128,3), 256, 0, stream>>>((const ushort*)fb,
                W2T + (size_t)l*MLPD*DIM, b2 + l*DIM, ls2 + l*DIM, xres);
    }
}

// Round 10
// 796.519 us; speedup vs baseline: 1.1523x; 1.1523x over previous
//
#include <hip/hip_runtime.h>
#include <hip/hip_bf16.h>

#define DEPTH   6
#define DIM     192
#define HEADS   12
#define DH      16
#define MLPD    768
#define SEQ     256
#define BATCH   32
#define ROWS    (BATCH*SEQ)   // 8192

typedef __attribute__((ext_vector_type(8))) short short8;
typedef __attribute__((ext_vector_type(4))) float f32x4;
typedef __attribute__((ext_vector_type(4))) _Float16 half4;
typedef __hip_bfloat16 bf16_t;
typedef _Float16 f16_t;

__device__ __forceinline__ bf16_t f2b(float v){ return __float2bfloat16(v); }
__device__ __forceinline__ ushort f2u(float v){
    union{ bf16_t b; ushort u; } w; w.b = __float2bfloat16(v); return w.u;
}
__device__ __forceinline__ f16_t u2h(ushort u){ union{ ushort u; f16_t h; } w; w.u = u; return w.h; }
__device__ __forceinline__ ushort h2u(f16_t h){ union{ ushort u; f16_t h; } w; w.h = h; return w.u; }

// async global->LDS, 16B per lane. LDS dest = wave-uniform base + lane*16B.
__device__ __forceinline__ void async16(ushort* lds, const ushort* gp){
    __builtin_amdgcn_global_load_lds(
        (const __attribute__((address_space(1))) uint*)gp,
        (__attribute__((address_space(3))) uint*)lds, 16, 0, 0);
}

// ---------------- residual init ----------------
__global__ void copy_kernel(const float* __restrict__ x, float* __restrict__ xr, int n){
    int i = blockIdx.x*256 + threadIdx.x;
    if (i < n) xr[i] = x[i];
}

// ---------------- weight transpose-convert: W[l][K][N] fp32 -> WT[l][N][K] bf16 ----
__global__ __launch_bounds__(256) void wt_kernel(const float* __restrict__ W,
        ushort* __restrict__ WT, int K, int N){
    __shared__ ushort T[64*72];
    int l = blockIdx.z;
    const float* src = W + ((size_t)l*K + blockIdx.x*64)*N + blockIdx.y*64;
    ushort* dst = WT + ((size_t)l*N + blockIdx.y*64)*K + blockIdx.x*64;
    int tid = threadIdx.x;
    int r = tid >> 2, c4 = (tid & 3)*16;
    #pragma unroll
    for (int u=0; u<4; u++){
        float4 v = *(const float4*)(src + (size_t)r*N + c4 + u*4);
        T[(c4+u*4+0)*72 + r] = f2u(v.x);
        T[(c4+u*4+1)*72 + r] = f2u(v.y);
        T[(c4+u*4+2)*72 + r] = f2u(v.z);
        T[(c4+u*4+3)*72 + r] = f2u(v.w);
    }
    __syncthreads();
    int n = tid >> 2, k8 = (tid & 3)*16;
    #pragma unroll
    for (int u=0; u<2; u++)
        *(uint4*)(dst + (size_t)n*K + k8 + u*8) = *(uint4*)&T[n*72 + k8 + u*8];
}

// ---------------- fused LN + GEMM, column-looping (K = DIM = 192), R8 staging ------
// MODE 0: QKV -> q (f16 [row][192]), k (f16 [row][192]), vT (f16 [b][192][256])
// MODE 1: W1  -> +bias, exact GELU, bf16 to out0 (stride MLPD)
template<int MODE, int NT>
__global__ __launch_bounds__(256) void gemm_ln_kernel(
        const float* __restrict__ xres, const float* __restrict__ ln_g,
        const float* __restrict__ ln_b, const ushort* __restrict__ BT0,
        const ushort* __restrict__ BT1, const float* __restrict__ bias,
        f16_t* __restrict__ out0, f16_t* __restrict__ out1,
        f16_t* __restrict__ out2){
    __shared__ ushort As[64*200];      // LN'd A rows, stride 200 (2-way banks)
    __shared__ ushort Bs[2][6*2048];   // double-buffered N-tile (full K)
    int tid = threadIdx.x, lane = tid & 63, w = tid >> 6;
    int bm = blockIdx.x*64;
    int tile0 = blockIdx.y*NT;
    auto issueB = [&](int t, int buf){
        int bn = (tile0 + t)*64;
        const ushort* bt; int bnl;
        if (MODE == 0 && bn >= DIM){ bt = BT1; bnl = bn - DIM; }
        else { bt = BT0; bnl = bn; }
        const ushort* bp = bt + (size_t)(bnl + (tid>>2))*DIM + (tid&3)*8;
        #pragma unroll
        for (int c=0; c<6; c++)
            async16(&Bs[buf][c*2048 + tid*8], bp + c*32);
    };
    issueB(0, 0);
    // LN prologue: each block LNs its 64 rows ONCE
    float g0 = ln_g[lane], g1 = ln_g[lane+64], g2 = ln_g[lane+128];
    float e0 = ln_b[lane], e1 = ln_b[lane+64], e2 = ln_b[lane+128];
    for (int it = 0; it < 16; it++){
        int r = (w<<4) + it;
        const float* xr = xres + (size_t)(bm + r)*DIM;
        float v0 = xr[lane], v1 = xr[lane+64], v2 = xr[lane+128];
        float s = v0+v1+v2;
        #pragma unroll
        for (int off=32; off; off>>=1) s += __shfl_xor(s, off, 64);
        float m = s*(1.0f/192.0f);
        float d0=v0-m, d1=v1-m, d2=v2-m;
        float q = d0*d0+d1*d1+d2*d2;
        #pragma unroll
        for (int off=32; off; off>>=1) q += __shfl_xor(q, off, 64);
        float inv = rsqrtf(q*(1.0f/192.0f) + 1e-5f);
        ushort* dst = &As[r*200];
        dst[lane]     = f2u(d0*inv*g0 + e0);
        dst[lane+64]  = f2u(d1*inv*g1 + e1);
        dst[lane+128] = f2u(d2*inv*g2 + e2);
    }
    __syncthreads();   // drains tile-0 asyncs + As visible
    int wrow = w >> 1, wcol = w & 1;
    int quad = lane >> 4, mr = lane & 15;
    for (int t = 0; t < NT; t++){
        if (t+1 < NT) issueB(t+1, (t+1)&1);
        const ushort* B = Bs[t&1];
        f32x4 acc[2][2] = {};
        #pragma unroll
        for (int c = 0; c < 6; c++){
            short8 a0 = *(const short8*)&As[(wrow*32+mr)*200    + c*32 + quad*8];
            short8 a1 = *(const short8*)&As[(wrow*32+16+mr)*200 + c*32 + quad*8];
            short8 b0 = *(const short8*)&B[c*2048 + (wcol*32+mr)*32    + quad*8];
            short8 b1 = *(const short8*)&B[c*2048 + (wcol*32+16+mr)*32 + quad*8];
            acc[0][0] = __builtin_amdgcn_mfma_f32_16x16x32_bf16(a0, b0, acc[0][0], 0,0,0);
            acc[0][1] = __builtin_amdgcn_mfma_f32_16x16x32_bf16(a0, b1, acc[0][1], 0,0,0);
            acc[1][0] = __builtin_amdgcn_mfma_f32_16x16x32_bf16(a1, b0, acc[1][0], 0,0,0);
            acc[1][1] = __builtin_amdgcn_mfma_f32_16x16x32_bf16(a1, b1, acc[1][1], 0,0,0);
        }
        int bn = (tile0 + t)*64;
        #pragma unroll
        for (int rr=0; rr<2; rr++){
            #pragma unroll
            for (int cc=0; cc<2; cc++){
                int col = bn + wcol*32 + cc*16 + mr;
                if (MODE == 0){
                    if (col < DIM){
                        #pragma unroll
                        for (int tt=0; tt<4; tt++){
                            int row = bm + wrow*32 + rr*16 + quad*4 + tt;
                            out0[(size_t)row*DIM + col] = (f16_t)acc[rr][cc][tt];
                        }
                    } else if (col < 2*DIM){
                        #pragma unroll
                        for (int tt=0; tt<4; tt++){
                            int row = bm + wrow*32 + rr*16 + quad*4 + tt;
                            out1[(size_t)row*DIM + (col - DIM)] = (f16_t)acc[rr][cc][tt];
                        }
                    } else {
                        // V transposed: vT[b][vcol][j], rows consecutive over tt
                        int vcol = col - 2*DIM;
                        int row0 = bm + wrow*32 + rr*16 + quad*4;
                        int bb = row0 >> 8, rloc = row0 & 255;
                        union { ushort4 v; f16_t h[4]; } pv;
                        #pragma unroll
                        for (int tt=0; tt<4; tt++) pv.h[tt] = (f16_t)acc[rr][cc][tt];
                        *(ushort4*)((ushort*)out2 + ((size_t)bb*DIM + vcol)*SEQ + rloc) = pv.v;
                    }
                } else {
                    float bv = bias[col];
                    #pragma unroll
                    for (int tt=0; tt<4; tt++){
                        int row = bm + wrow*32 + rr*16 + quad*4 + tt;
                        float z = acc[rr][cc][tt] + bv;
                        ((bf16_t*)out0)[(size_t)row*MLPD + col] =
                            f2b(0.5f*z*(1.0f + erff(z*0.70710678118654752f)));
                    }
                }
            }
        }
        __syncthreads();
    }
}

// ---------------- GEMM + residual epilogue (R8 version): xres += (A@B^T+b)*ls ----
template<int ROUNDS>
__global__ __launch_bounds__(256) void gemm_a_kernel(
        const ushort* __restrict__ A, const ushort* __restrict__ BT,
        const float* __restrict__ bias, const float* __restrict__ ls,
        float* __restrict__ xres){
    const int K = ROUNDS*192;
    __shared__ ushort As[6*2048];
    __shared__ ushort Bs[6*2048];
    int tid = threadIdx.x, lane = tid & 63, w = tid >> 6;
    int wrow = w >> 1, wcol = w & 1;
    int bm = blockIdx.x*64, bn = blockIdx.y*64;
    int quad = lane >> 4, mr = lane & 15;
    const ushort* ap = A  + (size_t)(bm + (tid>>2))*K + (tid&3)*8;
    const ushort* bp = BT + (size_t)(bn + (tid>>2))*K + (tid&3)*8;
    f32x4 acc[2][2] = {};
    for (int r = 0; r < ROUNDS; r++){
        #pragma unroll
        for (int c=0; c<6; c++){
            async16(&As[c*2048 + tid*8], ap + r*192 + c*32);
            async16(&Bs[c*2048 + tid*8], bp + r*192 + c*32);
        }
        __syncthreads();
        #pragma unroll
        for (int c=0; c<6; c++){
            short8 a0 = *(const short8*)&As[c*2048 + (wrow*32+mr)*32    + quad*8];
            short8 a1 = *(const short8*)&As[c*2048 + (wrow*32+16+mr)*32 + quad*8];
            short8 b0 = *(const short8*)&Bs[c*2048 + (wcol*32+mr)*32    + quad*8];
            short8 b1 = *(const short8*)&Bs[c*2048 + (wcol*32+16+mr)*32 + quad*8];
            acc[0][0] = __builtin_amdgcn_mfma_f32_16x16x32_bf16(a0, b0, acc[0][0], 0,0,0);
            acc[0][1] = __builtin_amdgcn_mfma_f32_16x16x32_bf16(a0, b1, acc[0][1], 0,0,0);
            acc[1][0] = __builtin_amdgcn_mfma_f32_16x16x32_bf16(a1, b0, acc[1][0], 0,0,0);
            acc[1][1] = __builtin_amdgcn_mfma_f32_16x16x32_bf16(a1, b1, acc[1][1], 0,0,0);
        }
        if (r+1 < ROUNDS) __syncthreads();
    }
    #pragma unroll
    for (int rr=0; rr<2; rr++){
        #pragma unroll
        for (int cc=0; cc<2; cc++){
            int col = bn + wcol*32 + cc*16 + mr;
            float bv = bias[col], lv = ls[col];
            #pragma unroll
            for (int tt=0; tt<4; tt++){
                int row = bm + wrow*32 + rr*16 + quad*4 + tt;
                xres[(size_t)row*DIM + col] += (acc[rr][cc][tt] + bv)*lv;
            }
        }
    }
}

// ------- fused attention + Wo + residual (v5: direct Q/K/V, 5 barriers) -------
// block = (batch, 16-row i-tile), 512 threads / 8 waves. LDS: S + O + postT only.
#define SLAB    4488
#define IST     280
#define O_OFF   53856      // 12*SLAB
#define ROWP    200
#define POST_OFF 57056     // O_OFF + 16*ROWP
#define LTOT    57312

__global__ __launch_bounds__(512, 1) void attn_kernel(
        const f16_t* __restrict__ qb, const f16_t* __restrict__ kb,
        const f16_t* __restrict__ vT, const float* __restrict__ lsa,
        const float* __restrict__ pre, const float* __restrict__ post,
        const ushort* __restrict__ WoT, const float* __restrict__ bo,
        const float* __restrict__ ls1, float* __restrict__ xres){
    __shared__ ushort L[LTOT];
    int tid  = threadIdx.x;
    int lane = tid & 63, w = tid >> 6;
    int quad = lane >> 4, nr = lane & 15;
    int b  = blockIdx.x >> 4;
    int i0 = (blockIdx.x & 15) << 4;

    // stage postT (transposed, zero-padded 16x16) — fenced by the P1+P2 barrier
    if (tid < 256){
        int gg = tid >> 4, hh = tid & 15;
        float v = (gg < 12 && hh < 12) ? post[hh*12 + gg] : 0.f;
        L[POST_OFF + tid] = h2u((f16_t)v);
    }

    // Q frags direct from global (lsa folded in regs)
    half4 qf[12];
    {
        const f16_t* qrow = qb + (size_t)(b*SEQ + i0 + nr)*DIM;
        #pragma unroll
        for (int h=0; h<12; h++){
            half4 t = *(const half4*)(qrow + h*DH + quad*4);
            float sc = lsa[h];
            #pragma unroll
            for (int u=0; u<4; u++) t[u] = (f16_t)((float)t[u]*sc);
            qf[h] = t;
        }
    }

    // ---- P1+P2 fused: QK^T (K direct from global) + diag + mix_pre in regs ----
    #pragma unroll
    for (int sub = 0; sub < 2; sub++){
        int jg = w*32 + sub*16 + nr;
        const f16_t* krow = kb + (size_t)(b*SEQ + jg)*DIM;
        f32x4 acc[12];
        #pragma unroll
        for (int h=0; h<12; h++){
            half4 bv = *(const half4*)(krow + h*DH + quad*4);
            acc[h] = __builtin_amdgcn_mfma_f32_16x16x16f16(qf[h], bv, (f32x4){0,0,0,0}, 0,0,0);
        }
        #pragma unroll
        for (int t=0; t<4; t++){
            if (i0 + quad*4 + t == jg){
                #pragma unroll
                for (int h=0; h<12; h++) acc[h][t] = -1e-9f;
            }
        }
        #pragma unroll
        for (int g=0; g<12; g++){
            float s0=0.f, s1=0.f, s2=0.f, s3=0.f;
            #pragma unroll
            for (int h=0; h<12; h++){
                float p = pre[h*12+g];
                s0 += acc[h][0]*p; s1 += acc[h][1]*p;
                s2 += acc[h][2]*p; s3 += acc[h][3]*p;
            }
            ushort* sp = &L[g*SLAB + jg];
            sp[(quad*4+0)*IST] = h2u((f16_t)s0);
            sp[(quad*4+1)*IST] = h2u((f16_t)s1);
            sp[(quad*4+2)*IST] = h2u((f16_t)s2);
            sp[(quad*4+3)*IST] = h2u((f16_t)s3);
        }
    }
    __syncthreads();   // barrier A (S + postT visible)

    half4 postTf = *(const half4*)&L[POST_OFF + nr*16 + quad*4];

    // ---- softmax over j ----
    for (int r = w; r < 192; r += 8){
        int g = r >> 4, i = r & 15;
        ushort* sp = &L[g*SLAB + i*IST];
        ushort4 uv = *(ushort4*)&sp[lane*4];
        float e0 = __expf((float)u2h(uv.x));
        float e1 = __expf((float)u2h(uv.y));
        float e2 = __expf((float)u2h(uv.z));
        float e3 = __expf((float)u2h(uv.w));
        float ssum = e0+e1+e2+e3;
        #pragma unroll
        for (int off=32; off; off>>=1) ssum += __shfl_xor(ssum, off, 64);
        float rin = 1.0f/ssum;
        uv.x = h2u((f16_t)(e0*rin)); uv.y = h2u((f16_t)(e1*rin));
        uv.z = h2u((f16_t)(e2*rin)); uv.w = h2u((f16_t)(e3*rin));
        *(ushort4*)&sp[lane*4] = uv;
    }
    __syncthreads();   // barrier B

    // ---- P3: mix_post via MFMA, in-place; k-rows 12..15 are zero (predicated) ----
    for (int s = 0; s < 32; s++){
        int cb = s*8 + w;
        int i = cb >> 4, jb = cb & 15;
        int colbase = i*IST + jb*16 + nr;
        half4 bv = {(f16_t)0, (f16_t)0, (f16_t)0, (f16_t)0};
        if (quad < 3){
            #pragma unroll
            for (int t=0; t<4; t++) bv[t] = u2h(L[(quad*4+t)*SLAB + colbase]);
        }
        f32x4 cc = __builtin_amdgcn_mfma_f32_16x16x16f16(postTf, bv, (f32x4){0,0,0,0}, 0,0,0);
        if (quad < 3){
            #pragma unroll
            for (int t=0; t<4; t++) L[(quad*4+t)*SLAB + colbase] = h2u((f16_t)cc[t]);
        }
    }
    __syncthreads();   // barrier C

    // ---- P4: O = P @ V, V direct from global (vT[b][col][j], contiguous 8B) ----
    f32x4 oacc[2] = {{0,0,0,0},{0,0,0,0}};
    int g0 = w, g1 = (w < 4) ? 8 + w : -1;
    #pragma unroll
    for (int sl = 0; sl < 2; sl++){
        int g = sl ? g1 : g0;
        if (g < 0) continue;
        const f16_t* vcolp = vT + ((size_t)b*DIM + g*16 + nr)*SEQ;
        #pragma unroll
        for (int ks = 0; ks < 16; ks++){
            int jl = ks*16 + quad*4;
            half4 av = *(const half4*)&L[g*SLAB + nr*IST + jl];
            half4 bv = *(const half4*)(vcolp + jl);
            oacc[sl] = __builtin_amdgcn_mfma_f32_16x16x16f16(av, bv, oacc[sl], 0,0,0);
        }
    }
    __syncthreads();   // barrier D (S reads done before Wo-stage overwrite)

    // ---- Wo stage into dead S region + O (bf16) into O region ----
    {
        #pragma unroll
        for (int s = 0; s < 9; s++){
            int e = (tid + s*512)*8;          // [0, 36864)
            int c = e/12288, rem = e - c*12288;
            int n = rem >> 6, kk = rem & 63;
            async16(&L[e], WoT + (size_t)n*192 + c*64 + kk);
        }
        #pragma unroll
        for (int sl = 0; sl < 2; sl++){
            int g = sl ? g1 : g0;
            if (g < 0) continue;
            #pragma unroll
            for (int t=0; t<4; t++){
                int i = quad*4 + t;
                L[O_OFF + i*ROWP + g*16 + nr] = f2u(oacc[sl][t]);   // bf16 bits
            }
        }
    }
    __syncthreads();   // barrier E (drains WoT asyncs + O visible)

    // ---- O @ Wo: wave w owns col-tiles {w, w+8(if w<4)} ----
    {
        f32x4 wacc[2] = {{0,0,0,0},{0,0,0,0}};
        int ct0 = w, ct1 = (w < 4) ? 8 + w : -1;
        #pragma unroll
        for (int c = 0; c < 3; c++){
            #pragma unroll
            for (int sub = 0; sub < 2; sub++){
                int k0 = c*64 + sub*32;
                short8 av = *(const short8*)&L[O_OFF + nr*ROWP + k0 + quad*8];
                #pragma unroll
                for (int sl = 0; sl < 2; sl++){
                    int ct = sl ? ct1 : ct0;
                    if (ct < 0) continue;
                    short8 bv = *(const short8*)&L[c*12288 + (ct*16 + nr)*64 + sub*32 + quad*8];
                    wacc[sl] = __builtin_amdgcn_mfma_f32_16x16x32_bf16(av, bv, wacc[sl], 0,0,0);
                }
            }
        }
        #pragma unroll
        for (int sl = 0; sl < 2; sl++){
            int ct = sl ? ct1 : ct0;
            if (ct < 0) continue;
            int col = ct*16 + nr;
            float bv = bo[col], lv = ls1[col];
            #pragma unroll
            for (int t=0; t<4; t++){
                int row = b*SEQ + i0 + quad*4 + t;
                xres[(size_t)row*DIM + col] += (wacc[sl][t] + bv)*lv;
            }
        }
    }
}

extern "C" void kernel_launch(void* const* d_in, const int* in_sizes, int n_in,
                              void* d_out, int out_size, void* d_ws, size_t ws_size,
                              hipStream_t stream){
    const float* x    = (const float*)d_in[0];
    const float* ln1g = (const float*)d_in[1];
    const float* ln1b = (const float*)d_in[2];
    const float* Wq   = (const float*)d_in[3];
    const float* Wkv  = (const float*)d_in[4];
    const float* lsa  = (const float*)d_in[5];
    const float* pre  = (const float*)d_in[6];
    const float* post = (const float*)d_in[7];
    const float* Wo   = (const float*)d_in[8];
    const float* bo   = (const float*)d_in[9];
    const float* ls1  = (const float*)d_in[10];
    const float* ln2g = (const float*)d_in[11];
    const float* ln2b = (const float*)d_in[12];
    const float* W1   = (const float*)d_in[13];
    const float* b1   = (const float*)d_in[14];
    const float* W2   = (const float*)d_in[15];
    const float* b2   = (const float*)d_in[16];
    const float* ls2  = (const float*)d_in[17];
    float* xres = (float*)d_out;             // fp32 residual lives in d_out

    char* ws = (char*)d_ws;
    // union region: qb+kb+vT (QKV->attn) overlaps fb (W1->W2) — disjoint lifetimes
    f16_t*  qb = (f16_t*)ws;
    f16_t*  kb = (f16_t*)(ws + (size_t)ROWS*DIM*2);
    f16_t*  vT = (f16_t*)(ws + (size_t)2*ROWS*DIM*2);
    bf16_t* fb = (bf16_t*)ws;
    char* p = ws + (size_t)ROWS*MLPD*2;
    ushort* WqT  = (ushort*)p; p += (size_t)DEPTH*DIM*DIM*2;
    ushort* WkvT = (ushort*)p; p += (size_t)DEPTH*DIM*2*DIM*2;
    ushort* WoT  = (ushort*)p; p += (size_t)DEPTH*DIM*DIM*2;
    ushort* W1T  = (ushort*)p; p += (size_t)DEPTH*DIM*MLPD*2;
    ushort* W2T  = (ushort*)p; p += (size_t)DEPTH*MLPD*DIM*2;

    int ntot = ROWS*DIM;
    copy_kernel<<<ntot/256, 256, 0, stream>>>(x, xres, ntot);
    wt_kernel<<<dim3(3,3,6),  256, 0, stream>>>(Wq,  WqT,  DIM,  DIM);
    wt_kernel<<<dim3(3,6,6),  256, 0, stream>>>(Wkv, WkvT, DIM,  2*DIM);
    wt_kernel<<<dim3(3,3,6),  256, 0, stream>>>(Wo,  WoT,  DIM,  DIM);
    wt_kernel<<<dim3(3,12,6), 256, 0, stream>>>(W1,  W1T,  DIM,  MLPD);
    wt_kernel<<<dim3(12,3,6), 256, 0, stream>>>(W2,  W2T,  MLPD, DIM);
    for (int l = 0; l < DEPTH; l++){
        gemm_ln_kernel<0,3><<<dim3(128,3), 256, 0, stream>>>(xres,
                ln1g + l*DIM, ln1b + l*DIM,
                WqT + (size_t)l*DIM*DIM, WkvT + (size_t)l*DIM*2*DIM,
                nullptr, qb, kb, vT);
        attn_kernel<<<BATCH*(SEQ/16), 512, 0, stream>>>(qb, kb, vT, lsa + l*HEADS,
                pre + l*HEADS*HEADS, post + l*HEADS*HEADS,
                WoT + (size_t)l*DIM*DIM, bo + l*DIM, ls1 + l*DIM, xres);
        gemm_ln_kernel<1,4><<<dim3(128,3), 256, 0, stream>>>(xres,
                ln2g + l*DIM, ln2b + l*DIM,
                W1T + (size_t)l*DIM*MLPD, nullptr, b1 + l*MLPD, (f16_t*)fb, nullptr, nullptr);
        gemm_a_kernel<4><<<dim3(128,3), 256, 0, stream>>>((const ushort*)fb,
                W2T + (size_t)l*MLPD*DIM, b2 + l*DIM, ls2 + l*DIM, xres);
    }
}

// Round 11
// 707.769 us; speedup vs baseline: 1.2968x; 1.1254x over previous
//
#include <hip/hip_runtime.h>
#include <hip/hip_bf16.h>

#define DEPTH   6
#define DIM     192
#define HEADS   12
#define DH      16
#define MLPD    768
#define SEQ     256
#define BATCH   32
#define ROWS    (BATCH*SEQ)   // 8192

typedef __attribute__((ext_vector_type(8))) short short8;
typedef __attribute__((ext_vector_type(4))) float f32x4;
typedef __attribute__((ext_vector_type(4))) _Float16 half4;
typedef __hip_bfloat16 bf16_t;
typedef _Float16 f16_t;

__device__ __forceinline__ bf16_t f2b(float v){ return __float2bfloat16(v); }
__device__ __forceinline__ ushort f2u(float v){
    union{ bf16_t b; ushort u; } w; w.b = __float2bfloat16(v); return w.u;
}
__device__ __forceinline__ f16_t u2h(ushort u){ union{ ushort u; f16_t h; } w; w.u = u; return w.h; }
__device__ __forceinline__ ushort h2u(f16_t h){ union{ ushort u; f16_t h; } w; w.h = h; return w.u; }

// async global->LDS, 16B per lane. LDS dest = wave-uniform base + lane*16B.
__device__ __forceinline__ void async16(ushort* lds, const ushort* gp){
    __builtin_amdgcn_global_load_lds(
        (const __attribute__((address_space(1))) uint*)gp,
        (__attribute__((address_space(3))) uint*)lds, 16, 0, 0);
}

// ---------------- residual init ----------------
__global__ void copy_kernel(const float* __restrict__ x, float* __restrict__ xr, int n){
    int i = blockIdx.x*256 + threadIdx.x;
    if (i < n) xr[i] = x[i];
}

// ---------------- weight transpose-convert, ALL matrices in one launch ----------
// W[l][K][N] fp32 -> WT[l][N][K] bf16, 64x64 tiles
__device__ __forceinline__ void wt_tile(const float* __restrict__ W,
        ushort* __restrict__ WT, int K, int N, int l, int tx, int ty,
        int tid, ushort* T){
    const float* src = W + ((size_t)l*K + tx*64)*N + ty*64;
    ushort* dst = WT + ((size_t)l*N + ty*64)*K + tx*64;
    int r = tid >> 2, c4 = (tid & 3)*16;
    #pragma unroll
    for (int u=0; u<4; u++){
        float4 v = *(const float4*)(src + (size_t)r*N + c4 + u*4);
        T[(c4+u*4+0)*72 + r] = f2u(v.x);
        T[(c4+u*4+1)*72 + r] = f2u(v.y);
        T[(c4+u*4+2)*72 + r] = f2u(v.z);
        T[(c4+u*4+3)*72 + r] = f2u(v.w);
    }
    __syncthreads();
    int n = tid >> 2, k8 = (tid & 3)*16;
    #pragma unroll
    for (int u=0; u<2; u++)
        *(uint4*)(dst + (size_t)n*K + k8 + u*8) = *(uint4*)&T[n*72 + k8 + u*8];
}

__global__ __launch_bounds__(256) void wt_all(
        const float* __restrict__ Wq, const float* __restrict__ Wkv,
        const float* __restrict__ Wo, const float* __restrict__ W1,
        const float* __restrict__ W2,
        ushort* __restrict__ WqT, ushort* __restrict__ WkvT,
        ushort* __restrict__ WoT, ushort* __restrict__ W1T,
        ushort* __restrict__ W2T){
    __shared__ ushort T[64*72];
    int id = blockIdx.x, l = blockIdx.y, tid = threadIdx.x;
    if (id < 9)       wt_tile(Wq,  WqT,  192, 192, l, id/3,       id%3,       tid, T);
    else if (id < 27) wt_tile(Wkv, WkvT, 192, 384, l, (id-9)/6,   (id-9)%6,   tid, T);
    else if (id < 36) wt_tile(Wo,  WoT,  192, 192, l, (id-27)/3,  (id-27)%3,  tid, T);
    else if (id < 72) wt_tile(W1,  W1T,  192, 768, l, (id-36)/12, (id-36)%12, tid, T);
    else              wt_tile(W2,  W2T,  768, 192, l, (id-72)/3,  (id-72)%3,  tid, T);
}

// ---------------- fused LN + GEMM, column-looping (K = DIM = 192) — R8 exact ------
// MODE 0: QKV -> out0 (f16 stride 192) for cols<192, else out1 (f16 stride 384)
// MODE 1: W1  -> +bias, exact GELU, bf16 to out0 (stride MLPD)
template<int MODE, int NT>
__global__ __launch_bounds__(256) void gemm_ln_kernel(
        const float* __restrict__ xres, const float* __restrict__ ln_g,
        const float* __restrict__ ln_b, const ushort* __restrict__ BT0,
        const ushort* __restrict__ BT1, const float* __restrict__ bias,
        f16_t* __restrict__ out0, f16_t* __restrict__ out1){
    __shared__ ushort As[64*200];      // LN'd A rows, stride 200 (2-way banks)
    __shared__ ushort Bs[2][6*2048];   // double-buffered N-tile (full K)
    int tid = threadIdx.x, lane = tid & 63, w = tid >> 6;
    int bm = blockIdx.x*64;
    int tile0 = blockIdx.y*NT;
    auto issueB = [&](int t, int buf){
        int bn = (tile0 + t)*64;
        const ushort* bt; int bnl;
        if (MODE == 0 && bn >= DIM){ bt = BT1; bnl = bn - DIM; }
        else { bt = BT0; bnl = bn; }
        const ushort* bp = bt + (size_t)(bnl + (tid>>2))*DIM + (tid&3)*8;
        #pragma unroll
        for (int c=0; c<6; c++)
            async16(&Bs[buf][c*2048 + tid*8], bp + c*32);
    };
    issueB(0, 0);
    float g0 = ln_g[lane], g1 = ln_g[lane+64], g2 = ln_g[lane+128];
    float e0 = ln_b[lane], e1 = ln_b[lane+64], e2 = ln_b[lane+128];
    for (int it = 0; it < 16; it++){
        int r = (w<<4) + it;
        const float* xr = xres + (size_t)(bm + r)*DIM;
        float v0 = xr[lane], v1 = xr[lane+64], v2 = xr[lane+128];
        float s = v0+v1+v2;
        #pragma unroll
        for (int off=32; off; off>>=1) s += __shfl_xor(s, off, 64);
        float m = s*(1.0f/192.0f);
        float d0=v0-m, d1=v1-m, d2=v2-m;
        float q = d0*d0+d1*d1+d2*d2;
        #pragma unroll
        for (int off=32; off; off>>=1) q += __shfl_xor(q, off, 64);
        float inv = rsqrtf(q*(1.0f/192.0f) + 1e-5f);
        ushort* dst = &As[r*200];
        dst[lane]     = f2u(d0*inv*g0 + e0);
        dst[lane+64]  = f2u(d1*inv*g1 + e1);
        dst[lane+128] = f2u(d2*inv*g2 + e2);
    }
    __syncthreads();   // drains tile-0 asyncs + As visible
    int wrow = w >> 1, wcol = w & 1;
    int quad = lane >> 4, mr = lane & 15;
    for (int t = 0; t < NT; t++){
        if (t+1 < NT) issueB(t+1, (t+1)&1);
        const ushort* B = Bs[t&1];
        f32x4 acc[2][2] = {};
        #pragma unroll
        for (int c = 0; c < 6; c++){
            short8 a0 = *(const short8*)&As[(wrow*32+mr)*200    + c*32 + quad*8];
            short8 a1 = *(const short8*)&As[(wrow*32+16+mr)*200 + c*32 + quad*8];
            short8 b0 = *(const short8*)&B[c*2048 + (wcol*32+mr)*32    + quad*8];
            short8 b1 = *(const short8*)&B[c*2048 + (wcol*32+16+mr)*32 + quad*8];
            acc[0][0] = __builtin_amdgcn_mfma_f32_16x16x32_bf16(a0, b0, acc[0][0], 0,0,0);
            acc[0][1] = __builtin_amdgcn_mfma_f32_16x16x32_bf16(a0, b1, acc[0][1], 0,0,0);
            acc[1][0] = __builtin_amdgcn_mfma_f32_16x16x32_bf16(a1, b0, acc[1][0], 0,0,0);
            acc[1][1] = __builtin_amdgcn_mfma_f32_16x16x32_bf16(a1, b1, acc[1][1], 0,0,0);
        }
        int bn = (tile0 + t)*64;
        #pragma unroll
        for (int rr=0; rr<2; rr++){
            #pragma unroll
            for (int cc=0; cc<2; cc++){
                int col = bn + wcol*32 + cc*16 + mr;
                if (MODE == 0){
                    f16_t* op; size_t st;
                    if (col < DIM){ op = out0 + col; st = DIM; }
                    else          { op = out1 + (col - DIM); st = 2*DIM; }
                    #pragma unroll
                    for (int tt=0; tt<4; tt++){
                        int row = bm + wrow*32 + rr*16 + quad*4 + tt;
                        op[(size_t)row*st] = (f16_t)acc[rr][cc][tt];
                    }
                } else {
                    float bv = bias[col];
                    #pragma unroll
                    for (int tt=0; tt<4; tt++){
                        int row = bm + wrow*32 + rr*16 + quad*4 + tt;
                        float z = acc[rr][cc][tt] + bv;
                        ((bf16_t*)out0)[(size_t)row*MLPD + col] =
                            f2b(0.5f*z*(1.0f + erff(z*0.70710678118654752f)));
                    }
                }
            }
        }
        __syncthreads();
    }
}

// ---------------- GEMM + residual epilogue (R8 exact): xres += (A@B^T+b)*ls ----
template<int ROUNDS>
__global__ __launch_bounds__(256) void gemm_a_kernel(
        const ushort* __restrict__ A, const ushort* __restrict__ BT,
        const float* __restrict__ bias, const float* __restrict__ ls,
        float* __restrict__ xres){
    const int K = ROUNDS*192;
    __shared__ ushort As[6*2048];
    __shared__ ushort Bs[6*2048];
    int tid = threadIdx.x, lane = tid & 63, w = tid >> 6;
    int wrow = w >> 1, wcol = w & 1;
    int bm = blockIdx.x*64, bn = blockIdx.y*64;
    int quad = lane >> 4, mr = lane & 15;
    const ushort* ap = A  + (size_t)(bm + (tid>>2))*K + (tid&3)*8;
    const ushort* bp = BT + (size_t)(bn + (tid>>2))*K + (tid&3)*8;
    f32x4 acc[2][2] = {};
    for (int r = 0; r < ROUNDS; r++){
        #pragma unroll
        for (int c=0; c<6; c++){
            async16(&As[c*2048 + tid*8], ap + r*192 + c*32);
            async16(&Bs[c*2048 + tid*8], bp + r*192 + c*32);
        }
        __syncthreads();
        #pragma unroll
        for (int c=0; c<6; c++){
            short8 a0 = *(const short8*)&As[c*2048 + (wrow*32+mr)*32    + quad*8];
            short8 a1 = *(const short8*)&As[c*2048 + (wrow*32+16+mr)*32 + quad*8];
            short8 b0 = *(const short8*)&Bs[c*2048 + (wcol*32+mr)*32    + quad*8];
            short8 b1 = *(const short8*)&Bs[c*2048 + (wcol*32+16+mr)*32 + quad*8];
            acc[0][0] = __builtin_amdgcn_mfma_f32_16x16x32_bf16(a0, b0, acc[0][0], 0,0,0);
            acc[0][1] = __builtin_amdgcn_mfma_f32_16x16x32_bf16(a0, b1, acc[0][1], 0,0,0);
            acc[1][0] = __builtin_amdgcn_mfma_f32_16x16x32_bf16(a1, b0, acc[1][0], 0,0,0);
            acc[1][1] = __builtin_amdgcn_mfma_f32_16x16x32_bf16(a1, b1, acc[1][1], 0,0,0);
        }
        if (r+1 < ROUNDS) __syncthreads();
    }
    #pragma unroll
    for (int rr=0; rr<2; rr++){
        #pragma unroll
        for (int cc=0; cc<2; cc++){
            int col = bn + wcol*32 + cc*16 + mr;
            float bv = bias[col], lv = ls[col];
            #pragma unroll
            for (int tt=0; tt<4; tt++){
                int row = bm + wrow*32 + rr*16 + quad*4 + tt;
                xres[(size_t)row*DIM + col] += (acc[rr][cc][tt] + bv)*lv;
            }
        }
    }
}

// ------- fused attention + Wo + residual (v6: R8 algorithm, 16 waves) -------
// block = (batch, 16-row i-tile), 1024 threads / 16 waves, 512 blocks.
// Each wave owns HALF of R8's per-wave work in every phase.
#define SLAB    4488
#define IST     280
#define KV_OFF  53856
#define ROWP    200
#define Q_OFF   66656
#define POST_OFF 70112
#define LTOT    71776

__global__ __launch_bounds__(1024, 1) void attn_kernel(
        const f16_t* __restrict__ qb, const f16_t* __restrict__ kvb,
        const float* __restrict__ lsa, const float* __restrict__ pre,
        const float* __restrict__ post, const ushort* __restrict__ WoT,
        const float* __restrict__ bo, const float* __restrict__ ls1,
        float* __restrict__ xres){
    __shared__ ushort L[LTOT];
    int tid  = threadIdx.x;
    int lane = tid & 63, w = tid >> 6;      // w in [0,16)
    int quad = lane >> 4, nr = lane & 15;
    int b  = blockIdx.x >> 4;
    int i0 = (blockIdx.x & 15) << 4;

    // zero KV..end: P3's h=12..15 OOB reads must always see finite f16
    {
        uint* Z = (uint*)&L[KV_OFF];
        for (int k = tid; k < (LTOT - KV_OFF)/2; k += 1024) Z[k] = 0;
    }
    __syncthreads();

    // stage Q (lsa folded) tid<384; postT (transposed, zero-padded) tid in [384,512)
    if (tid < 384){
        int e = tid*8, i = e/DIM, d = e%DIM, hh = d >> 4;
        float sc = lsa[hh];
        union { uint4 v; f16_t h[8]; } iv, ov;
        iv.v = *(const uint4*)(qb + (size_t)(b*SEQ + i0 + i)*DIM + d);
        #pragma unroll
        for (int u=0; u<8; u++) ov.h[u] = (f16_t)((float)iv.h[u]*sc);
        *(uint4*)&L[Q_OFF + i*ROWP + d] = ov.v;
    } else if (tid < 512){
        for (int k = tid-384; k < 256; k += 128){
            int gg = k >> 4, hh = k & 15;
            if (gg < 12 && hh < 12)
                L[POST_OFF + k] = h2u((f16_t)post[hh*12+gg]);
        }
    }
    auto stage_kv = [&](int c, int coloff){
        for (int u = tid; u < 1536; u += 1024){
            int e = u*8;
            int j = e/DIM, d = e%DIM;
            uint4 v = *(const uint4*)(kvb + (size_t)(b*SEQ + c*64 + j)*(2*DIM) + coloff + d);
            *(uint4*)&L[KV_OFF + j*ROWP + d] = v;
        }
    };
    __syncthreads();

    // Q frags for all 12 heads; postT frag
    half4 qf[12];
    #pragma unroll
    for (int h=0; h<12; h++)
        qf[h] = *(const half4*)&L[Q_OFF + nr*ROWP + h*16 + quad*4];
    half4 postTf = *(const half4*)&L[POST_OFF + nr*16 + quad*4];

    // ---- P1+P2 fused: wave owns 16-j slice; QK^T (K direct global) + diag + mix_pre
    {
        int jg = w*16 + nr;
        const f16_t* krow = kvb + (size_t)(b*SEQ + jg)*(2*DIM);
        f32x4 acc[12];
        #pragma unroll
        for (int h=0; h<12; h++){
            half4 bv = *(const half4*)(krow + h*DH + quad*4);
            acc[h] = __builtin_amdgcn_mfma_f32_16x16x16f16(qf[h], bv, (f32x4){0,0,0,0}, 0,0,0);
        }
        #pragma unroll
        for (int t=0; t<4; t++){
            if (i0 + quad*4 + t == jg){
                #pragma unroll
                for (int h=0; h<12; h++) acc[h][t] = -1e-9f;
            }
        }
        #pragma unroll
        for (int g=0; g<12; g++){
            float s0=0.f, s1=0.f, s2=0.f, s3=0.f;
            #pragma unroll
            for (int h=0; h<12; h++){
                float p = pre[h*12+g];
                s0 += acc[h][0]*p; s1 += acc[h][1]*p;
                s2 += acc[h][2]*p; s3 += acc[h][3]*p;
            }
            ushort* sp = &L[g*SLAB + jg];
            sp[(quad*4+0)*IST] = h2u((f16_t)s0);
            sp[(quad*4+1)*IST] = h2u((f16_t)s1);
            sp[(quad*4+2)*IST] = h2u((f16_t)s2);
            sp[(quad*4+3)*IST] = h2u((f16_t)s3);
        }
    }
    __syncthreads();

    // ---- softmax over j: 12 rows per wave ----
    for (int r = w; r < 192; r += 16){
        int g = r >> 4, i = r & 15;
        ushort* sp = &L[g*SLAB + i*IST];
        ushort4 uv = *(ushort4*)&sp[lane*4];
        float e0 = __expf((float)u2h(uv.x));
        float e1 = __expf((float)u2h(uv.y));
        float e2 = __expf((float)u2h(uv.z));
        float e3 = __expf((float)u2h(uv.w));
        float ssum = e0+e1+e2+e3;
        #pragma unroll
        for (int off=32; off; off>>=1) ssum += __shfl_xor(ssum, off, 64);
        float rin = 1.0f/ssum;
        uv.x = h2u((f16_t)(e0*rin)); uv.y = h2u((f16_t)(e1*rin));
        uv.z = h2u((f16_t)(e2*rin)); uv.w = h2u((f16_t)(e3*rin));
        *(ushort4*)&sp[lane*4] = uv;
    }
    __syncthreads();

    // ---- P3: mix_post via MFMA, in-place; 16 cell-blocks per wave ----
    for (int s = 0; s < 16; s++){
        int cb = s*16 + w;
        int i = cb >> 4, jb = cb & 15;
        int colbase = i*IST + jb*16 + nr;
        half4 bv;
        #pragma unroll
        for (int t=0; t<4; t++) bv[t] = u2h(L[(quad*4+t)*SLAB + colbase]);
        f32x4 cc = __builtin_amdgcn_mfma_f32_16x16x16f16(postTf, bv, (f32x4){0,0,0,0}, 0,0,0);
        if (quad < 3){
            #pragma unroll
            for (int t=0; t<4; t++) L[(quad*4+t)*SLAB + colbase] = h2u((f16_t)cc[t]);
        }
    }
    __syncthreads();

    // ---- P4: O = P @ V, V staged in LDS; wave w < 12 owns head w ----
    f32x4 oacc = {0,0,0,0};
    for (int c = 0; c < 4; c++){
        stage_kv(c, DIM);
        __syncthreads();
        if (w < 12){
            int g = w;
            #pragma unroll
            for (int ks = 0; ks < 4; ks++){
                int jl = ks*16 + quad*4;
                half4 av = *(const half4*)&L[g*SLAB + nr*IST + c*64 + jl];
                half4 bv;
                #pragma unroll
                for (int t=0; t<4; t++) bv[t] = u2h(L[KV_OFF + (jl+t)*ROWP + g*16 + nr]);
                oacc = __builtin_amdgcn_mfma_f32_16x16x16f16(av, bv, oacc, 0,0,0);
            }
        }
        __syncthreads();
    }

    // ---- Wo stage into dead S region + O (bf16) into Q region ----
    {
        for (int u = tid; u < 4608; u += 1024){
            int e = u*8;
            int c = e/12288, rem = e - c*12288;
            int n = rem >> 6, kk = rem & 63;
            async16(&L[e], WoT + (size_t)n*192 + c*64 + kk);
        }
        if (w < 12){
            int g = w;
            #pragma unroll
            for (int t=0; t<4; t++){
                int i = quad*4 + t;
                L[Q_OFF + i*ROWP + g*16 + nr] = f2u(oacc[t]);   // bf16 bits
            }
        }
    }
    __syncthreads();   // drains WoT asyncs + O visible

    // ---- O @ Wo: wave w < 12 owns col-tile w; epilogue xres += (.+bo)*ls1 ----
    if (w < 12){
        f32x4 wacc = {0,0,0,0};
        int ct = w;
        #pragma unroll
        for (int c = 0; c < 3; c++){
            #pragma unroll
            for (int sub = 0; sub < 2; sub++){
                int k0 = c*64 + sub*32;
                short8 av = *(const short8*)&L[Q_OFF + nr*ROWP + k0 + quad*8];
                short8 bv = *(const short8*)&L[c*12288 + (ct*16 + nr)*64 + sub*32 + quad*8];
                wacc = __builtin_amdgcn_mfma_f32_16x16x32_bf16(av, bv, wacc, 0,0,0);
            }
        }
        int col = ct*16 + nr;
        float bv2 = bo[col], lv = ls1[col];
        #pragma unroll
        for (int t=0; t<4; t++){
            int row = b*SEQ + i0 + quad*4 + t;
            xres[(size_t)row*DIM + col] += (wacc[t] + bv2)*lv;
        }
    }
}

extern "C" void kernel_launch(void* const* d_in, const int* in_sizes, int n_in,
                              void* d_out, int out_size, void* d_ws, size_t ws_size,
                              hipStream_t stream){
    const float* x    = (const float*)d_in[0];
    const float* ln1g = (const float*)d_in[1];
    const float* ln1b = (const float*)d_in[2];
    const float* Wq   = (const float*)d_in[3];
    const float* Wkv  = (const float*)d_in[4];
    const float* lsa  = (const float*)d_in[5];
    const float* pre  = (const float*)d_in[6];
    const float* post = (const float*)d_in[7];
    const float* Wo   = (const float*)d_in[8];
    const float* bo   = (const float*)d_in[9];
    const float* ls1  = (const float*)d_in[10];
    const float* ln2g = (const float*)d_in[11];
    const float* ln2b = (const float*)d_in[12];
    const float* W1   = (const float*)d_in[13];
    const float* b1   = (const float*)d_in[14];
    const float* W2   = (const float*)d_in[15];
    const float* b2   = (const float*)d_in[16];
    const float* ls2  = (const float*)d_in[17];
    float* xres = (float*)d_out;             // fp32 residual lives in d_out

    char* ws = (char*)d_ws;
    // union region: qb+kvb (QKV->attn) overlaps fb (W1->W2) — disjoint lifetimes
    f16_t*  qb  = (f16_t*)ws;
    f16_t*  kvb = (f16_t*)(ws + (size_t)ROWS*DIM*2);
    bf16_t* fb  = (bf16_t*)ws;
    char* p = ws + (size_t)ROWS*MLPD*2;
    ushort* WqT  = (ushort*)p; p += (size_t)DEPTH*DIM*DIM*2;
    ushort* WkvT = (ushort*)p; p += (size_t)DEPTH*DIM*2*DIM*2;
    ushort* WoT  = (ushort*)p; p += (size_t)DEPTH*DIM*DIM*2;
    ushort* W1T  = (ushort*)p; p += (size_t)DEPTH*DIM*MLPD*2;
    ushort* W2T  = (ushort*)p; p += (size_t)DEPTH*MLPD*DIM*2;

    int ntot = ROWS*DIM;
    copy_kernel<<<ntot/256, 256, 0, stream>>>(x, xres, ntot);
    wt_all<<<dim3(108, 6), 256, 0, stream>>>(Wq, Wkv, Wo, W1, W2,
                                             WqT, WkvT, WoT, W1T, W2T);
    for (int l = 0; l < DEPTH; l++){
        gemm_ln_kernel<0,3><<<dim3(128,3), 256, 0, stream>>>(xres,
                ln1g + l*DIM, ln1b + l*DIM,
                WqT + (size_t)l*DIM*DIM, WkvT + (size_t)l*DIM*2*DIM,
                nullptr, qb, kvb);
        attn_kernel<<<BATCH*(SEQ/16), 1024, 0, stream>>>(qb, kvb, lsa + l*HEADS,
                pre + l*HEADS*HEADS, post + l*HEADS*HEADS,
                WoT + (size_t)l*DIM*DIM, bo + l*DIM, ls1 + l*DIM, xres);
        gemm_ln_kernel<1,4><<<dim3(128,3), 256, 0, stream>>>(xres,
                ln2g + l*DIM, ln2b + l*DIM,
                W1T + (size_t)l*DIM*MLPD, nullptr, b1 + l*MLPD, (f16_t*)fb, nullptr);
        gemm_a_kernel<4><<<dim3(128,3), 256, 0, stream>>>((const ushort*)fb,
                W2T + (size_t)l*MLPD*DIM, b2 + l*DIM, ls2 + l*DIM, xres);
    }
}